// Round 1
// baseline (223.116 us; speedup 1.0000x reference)
//
#include <hip/hip_runtime.h>

#define HIDDEN   4096
#define RANK     256
#define G        16      // HIDDEN / RANK
#define TT       16      // tokens per block
#define NTHREADS 256

__global__ __launch_bounds__(NTHREADS, 4)
void mora_fused(const float* __restrict__ x,   // [T, HIDDEN]
                const float* __restrict__ M,   // [RANK, RANK] row-major
                float* __restrict__ out)       // [T, HIDDEN]
{
    __shared__ float4 comp4[TT][RANK / 4];     // 16 x 64 float4 = 16 KiB

    const int  tid  = threadIdx.x;
    const long tok0 = (long)blockIdx.x * TT;

    // ---- Phase 1: compressed[t][r] = sum_gi x[t][gi*256 + r] ----
    {
        const int rr = tid & 63;   // float4-column within rank (r = rr*4..rr*4+3)
        const int ts = tid >> 6;   // 0..3
        #pragma unroll
        for (int ti = 0; ti < TT / 4; ++ti) {
            const int t = ts * (TT / 4) + ti;
            const float4* xrow = (const float4*)(x + (tok0 + t) * HIDDEN);
            float4 a = xrow[rr];
            #pragma unroll
            for (int gi = 1; gi < G; ++gi) {
                float4 v = xrow[gi * 64 + rr];
                a.x += v.x; a.y += v.y; a.z += v.z; a.w += v.w;
            }
            comp4[t][rr] = a;
        }
    }
    __syncthreads();

    // ---- Phase 2: out[t][k] = sum_r comp[t][r] * M[r][k] ----
    // thread owns columns k and k+128, and TT/2 tokens (half th)
    const int k  = tid & 127;
    const int th = tid >> 7;

    float acc0[TT / 2];
    float acc1[TT / 2];
    #pragma unroll
    for (int i = 0; i < TT / 2; ++i) { acc0[i] = 0.f; acc1[i] = 0.f; }

    for (int r4 = 0; r4 < RANK / 4; ++r4) {
        const float* mrow = M + (size_t)r4 * 4 * RANK;
        const float m0a = mrow[0 * RANK + k];
        const float m1a = mrow[1 * RANK + k];
        const float m2a = mrow[2 * RANK + k];
        const float m3a = mrow[3 * RANK + k];
        const float m0b = mrow[0 * RANK + k + 128];
        const float m1b = mrow[1 * RANK + k + 128];
        const float m2b = mrow[2 * RANK + k + 128];
        const float m3b = mrow[3 * RANK + k + 128];
        #pragma unroll
        for (int i = 0; i < TT / 2; ++i) {
            const int t = th * (TT / 2) + i;
            const float4 c = comp4[t][r4];   // wave-uniform broadcast read
            acc0[i] += c.x * m0a + c.y * m1a + c.z * m2a + c.w * m3a;
            acc1[i] += c.x * m0b + c.y * m1b + c.z * m2b + c.w * m3b;
        }
    }

    // ---- Phase 3: expanded write: dec[h] = out[h/16] ----
    #pragma unroll
    for (int i = 0; i < TT / 2; ++i) {
        const int t = th * (TT / 2) + i;
        float4* orow = (float4*)(out + (tok0 + t) * HIDDEN);
        const float4 v0 = make_float4(acc0[i], acc0[i], acc0[i], acc0[i]);
        const float4 v1 = make_float4(acc1[i], acc1[i], acc1[i], acc1[i]);
        #pragma unroll
        for (int j = 0; j < 4; ++j) {
            orow[(size_t)k * 4 + j]         = v0;   // h = k*16 + j*4 .. +3
            orow[(size_t)(k + 128) * 4 + j] = v1;
        }
    }
}

extern "C" void kernel_launch(void* const* d_in, const int* in_sizes, int n_in,
                              void* d_out, int out_size, void* d_ws, size_t ws_size,
                              hipStream_t stream) {
    const float* x = (const float*)d_in[0];
    const float* M = (const float*)d_in[1];
    float* out     = (float*)d_out;

    const int T    = in_sizes[0] / HIDDEN;  // 16384 tokens
    const int grid = T / TT;                // 1024 blocks

    hipLaunchKernelGGL(mora_fused, dim3(grid), dim3(NTHREADS), 0, stream,
                       x, M, out);
}

// Round 2
// 141.677 us; speedup vs baseline: 1.5748x; 1.5748x over previous
//
#include <hip/hip_runtime.h>

#define HIDDEN   4096
#define RANK     256
#define G        16      // HIDDEN / RANK
#define TT       8       // tokens per block
#define NTHREADS 256

__global__ __launch_bounds__(NTHREADS, 8)
void mora_fused(const float* __restrict__ x,   // [T, HIDDEN]
                const float* __restrict__ M,   // [RANK, RANK] row-major
                float* __restrict__ out)       // [T, HIDDEN]
{
    __shared__ float4 comp4[TT][RANK / 4];     // 8 x 64 float4 = 8 KiB
    __shared__ float  outstage[TT][RANK];      // 8 x 256 floats = 8 KiB

    const int  tid  = threadIdx.x;
    const long tok0 = (long)blockIdx.x * TT;

    // ---- Phase 1: compressed[t][r] = sum_gi x[t][gi*256 + r] ----
    // Coalesced: lanes 0..63 read consecutive float4 (1 KiB / wave inst).
    {
        const int rr = tid & 63;   // float4-column within rank
        const int ts = tid >> 6;   // 0..3, owns TT/4 = 2 tokens
        #pragma unroll
        for (int ti = 0; ti < TT / 4; ++ti) {
            const int t = ts * (TT / 4) + ti;
            const float4* xrow = (const float4*)(x + (tok0 + t) * HIDDEN);
            float4 a = xrow[rr];
            #pragma unroll
            for (int gi = 1; gi < G; ++gi) {
                float4 v = xrow[gi * 64 + rr];
                a.x += v.x; a.y += v.y; a.z += v.z; a.w += v.w;
            }
            comp4[t][rr] = a;
        }
    }
    __syncthreads();

    // ---- Phase 2: out[t][k] = sum_r comp[t][r] * M[r][k] ----
    // Thread owns exactly ONE column k = tid. M is read exactly once per
    // block, coalesced (lanes read consecutive floats of a row). comp reads
    // are same-address LDS broadcasts (free).
    const int k = tid;
    float acc[TT];
    #pragma unroll
    for (int t = 0; t < TT; ++t) acc[t] = 0.f;

    #pragma unroll 2
    for (int r4 = 0; r4 < RANK / 4; ++r4) {
        const float* mcol = M + (size_t)r4 * 4 * RANK + k;
        const float m0 = mcol[0 * RANK];
        const float m1 = mcol[1 * RANK];
        const float m2 = mcol[2 * RANK];
        const float m3 = mcol[3 * RANK];
        #pragma unroll
        for (int t = 0; t < TT; ++t) {
            const float4 c = comp4[t][r4];   // wave-uniform broadcast
            acc[t] += c.x * m0 + c.y * m1 + c.z * m2 + c.w * m3;
        }
    }

    // ---- stage the 256-wide result rows in LDS ----
    #pragma unroll
    for (int t = 0; t < TT; ++t) outstage[t][k] = acc[t];
    __syncthreads();

    // ---- Phase 3: fully coalesced expanded write ----
    // Row is 1024 float4; thread writes float4 index p = tid + 256j with
    // value outstage[t][p>>2]. Wave writes contiguous 1 KiB per store.
    #pragma unroll
    for (int t = 0; t < TT; ++t) {
        float4* orow = (float4*)(out + (tok0 + t) * HIDDEN);
        #pragma unroll
        for (int j = 0; j < 4; ++j) {
            const float v = outstage[t][(tid >> 2) + 64 * j];
            orow[tid + 256 * j] = make_float4(v, v, v, v);
        }
    }
}

extern "C" void kernel_launch(void* const* d_in, const int* in_sizes, int n_in,
                              void* d_out, int out_size, void* d_ws, size_t ws_size,
                              hipStream_t stream) {
    const float* x = (const float*)d_in[0];
    const float* M = (const float*)d_in[1];
    float* out     = (float*)d_out;

    const int T    = in_sizes[0] / HIDDEN;  // 16384 tokens
    const int grid = T / TT;                // 2048 blocks

    hipLaunchKernelGGL(mora_fused, dim3(grid), dim3(NTHREADS), 0, stream,
                       x, M, out);
}